// Round 6
// baseline (13497.285 us; speedup 1.0000x reference)
//
#include <hip/hip_runtime.h>
#include <cstddef>
#include <cstdint>

// ---------------------------------------------------------------------------
// GATv2 x3 layers. R5:
//  - GEMM: 128x256 block, 256 thr, 4 waves of 128m x 64n (acc 4x2 f32x16).
//    Fixes LDS-read:MFMA ratio (R3 was 2.3x over LDS budget, this is 1.47x)
//    while keeping 2 blocks/CU (R4's 512-thr block had 1 -> regressed).
//  - layer-2 W packed once for all heads; layer-3 per-head (ws safety).
//  - layer-1 fp32 GEMM grouped 8 heads/launch; fused online-softmax edge.
// ---------------------------------------------------------------------------

#define HEADS 32
#define SLOPE_ATT 0.2f
#define SLOPE_ACT 0.01f

typedef __bf16 bf16_t;
typedef __bf16 bf16x8 __attribute__((ext_vector_type(8)));
typedef float f32x16 __attribute__((ext_vector_type(16)));

// ---------------- CSR build ----------------

__global__ __launch_bounds__(256) void init_counts_kernel(int* counts, int n) {
  int i = blockIdx.x * 256 + threadIdx.x;
  if (i < n) counts[i] = 1;  // self-loop
}

__global__ __launch_bounds__(256) void count_kernel(const int* __restrict__ dst, int* counts, int E) {
  int e = blockIdx.x * 256 + threadIdx.x;
  if (e < E) atomicAdd(&counts[dst[e]], 1);
}

__global__ __launch_bounds__(1024) void scan_kernel(const int* __restrict__ counts,
                                                    int* __restrict__ row_ptr,
                                                    int* __restrict__ cursor, int n) {
  __shared__ int sums[1024];
  int t = threadIdx.x;
  int per = (n + 1023) >> 10;
  int base = t * per;
  int s = 0;
  for (int i = 0; i < per; i++) { int idx = base + i; if (idx < n) s += counts[idx]; }
  sums[t] = s;
  __syncthreads();
  for (int off = 1; off < 1024; off <<= 1) {
    int v = (t >= off) ? sums[t - off] : 0;
    __syncthreads();
    sums[t] += v;
    __syncthreads();
  }
  int run = (t == 0) ? 0 : sums[t - 1];
  for (int i = 0; i < per; i++) {
    int idx = base + i;
    if (idx < n) { row_ptr[idx] = run; cursor[idx] = run; run += counts[idx]; }
  }
  if (t == 1023) row_ptr[n] = sums[1023];
}

__global__ __launch_bounds__(256) void scatter_edges_kernel(const int* __restrict__ ei, int* cursor,
                                                            int* col_src, int* col_dst, int E) {
  int e = blockIdx.x * 256 + threadIdx.x;
  if (e >= E) return;
  int src = ei[e], dst = ei[E + e];
  int pos = atomicAdd(&cursor[dst], 1);
  col_src[pos] = src;
  col_dst[pos] = dst;
}

__global__ __launch_bounds__(256) void scatter_loops_kernel(int* cursor, int* col_src, int* col_dst, int N) {
  int nid = blockIdx.x * 256 + threadIdx.x;
  if (nid >= N) return;
  int pos = atomicAdd(&cursor[nid], 1);
  col_src[pos] = nid;
  col_dst[pos] = nid;
}

// ---------------- split-bf16 pack: X[M,K] fp32 -> frag-major hi/lo ----------------
// index: (mtile*(K/8) + kchunk)*1024 + mlocal*8 + (k&7); Mpad = mtiles*128.

__global__ __launch_bounds__(256) void cvt_pack_kernel(const float* __restrict__ X,
                                                       bf16_t* __restrict__ hi,
                                                       bf16_t* __restrict__ lo,
                                                       int M, int Mpad, int K) {
  int t = blockIdx.x * 256 + threadIdx.x;
  int kchunks = K >> 3;
  int total = Mpad * kchunks;
  if (t >= total) return;
  int kc = t % kchunks;
  int m = t / kchunks;
  int mt = m >> 7, ml = m & 127;
  size_t o = ((size_t)(mt * kchunks + kc)) * 1024 + (size_t)ml * 8;
  float v[8];
  if (m < M) {
    float4 a = *(const float4*)(X + (size_t)m * K + kc * 8);
    float4 b = *(const float4*)(X + (size_t)m * K + kc * 8 + 4);
    v[0] = a.x; v[1] = a.y; v[2] = a.z; v[3] = a.w;
    v[4] = b.x; v[5] = b.y; v[6] = b.z; v[7] = b.w;
  } else {
#pragma unroll
    for (int i = 0; i < 8; i++) v[i] = 0.f;
  }
  union { bf16_t h[8]; float4 f; } uh, ul;
#pragma unroll
  for (int i = 0; i < 8; i++) {
    bf16_t h = (bf16_t)v[i];
    uh.h[i] = h;
    ul.h[i] = (bf16_t)(v[i] - (float)h);
  }
  *(float4*)(hi + o) = uh.f;
  *(float4*)(lo + o) = ul.f;
}

// ---------------- W pack (single head slice) ----------------
// B index: (ntile*(K/8) + kchunk)*1024 + nlocal*8 + (k&7); Npad = ntiles*128.

__global__ __launch_bounds__(256) void pack_w_kernel(const float* __restrict__ Wl,
                                                     const float* __restrict__ Wr,
                                                     bf16_t* __restrict__ hL, bf16_t* __restrict__ lL,
                                                     bf16_t* __restrict__ hR, bf16_t* __restrict__ lR,
                                                     int K, int C, int Npad, int ldW, int col0) {
  int side = blockIdx.y;
  const float* W = side ? Wr : Wl;
  bf16_t* Hi = side ? hR : hL;
  bf16_t* Lo = side ? lR : lL;
  int kchunks = K >> 3;
  int total = Npad * kchunks;
  int t = blockIdx.x * 256 + threadIdx.x;
  if (t >= total) return;
  int n = t % Npad, kc = t / Npad;
  int nt = n >> 7, nl = n & 127;
  size_t o = ((size_t)(nt * kchunks + kc)) * 1024 + (size_t)nl * 8;
  union { bf16_t h[8]; float4 f; } uh, ul;
#pragma unroll
  for (int kk = 0; kk < 8; kk++) {
    int k = kc * 8 + kk;
    float v = (n < C) ? W[(size_t)k * ldW + col0 + n] : 0.f;
    bf16_t h = (bf16_t)v;
    uh.h[kk] = h;
    ul.h[kk] = (bf16_t)(v - (float)h);
  }
  *(float4*)(Hi + o) = uh.f;
  *(float4*)(Lo + o) = ul.f;
}

// ---------------- W pack, all heads (layer 2) ----------------
// per-head section of Npad*K elems at h*Npad*K; within: same frag-major format.

__global__ __launch_bounds__(256) void pack_w_all_kernel(const float* __restrict__ Wl,
                                                         const float* __restrict__ Wr,
                                                         bf16_t* __restrict__ hL, bf16_t* __restrict__ lL,
                                                         bf16_t* __restrict__ hR, bf16_t* __restrict__ lR,
                                                         int K, int C, int Npad, int ldW) {
  int side = blockIdx.y;
  const float* W = side ? Wr : Wl;
  bf16_t* Hi = side ? hR : hL;
  bf16_t* Lo = side ? lR : lL;
  int kchunks = K >> 3;
  int perhead = Npad * kchunks;
  int t = blockIdx.x * 256 + threadIdx.x;
  if (t >= HEADS * perhead) return;
  int h = t / perhead, rem = t % perhead;
  int n = rem % Npad, kc = rem / Npad;
  int nt = n >> 7, nl = n & 127;
  size_t o = (size_t)h * Npad * K + ((size_t)(nt * kchunks + kc)) * 1024 + (size_t)nl * 8;
  int col0 = h * C;
  union { bf16_t hh[8]; float4 f; } uh, ul;
#pragma unroll
  for (int kk = 0; kk < 8; kk++) {
    int k = kc * 8 + kk;
    float v = (n < C) ? W[(size_t)k * ldW + col0 + n] : 0.f;
    bf16_t hv = (bf16_t)v;
    uh.hh[kk] = hv;
    ul.hh[kk] = (bf16_t)(v - (float)hv);
  }
  *(float4*)(Hi + o) = uh.f;
  *(float4*)(Lo + o) = ul.f;
}

// ---------------- MFMA GEMM: 128m x 256n block, 256 thr, 4 waves of 128x64 ----
// acc 4x2 f32x16 (128 VGPR). LDS 48KB. Split-bf16: 3 MFMA per (A,B) frag pair.

__global__ __launch_bounds__(256) void gemm_mfma_v5(const bf16_t* __restrict__ Xh,
                                                    const bf16_t* __restrict__ Xl,
                                                    const bf16_t* __restrict__ BhL,
                                                    const bf16_t* __restrict__ BlL,
                                                    const bf16_t* __restrict__ BhR,
                                                    const bf16_t* __restrict__ BlR,
                                                    const float* __restrict__ bl,
                                                    const float* __restrict__ br,
                                                    float* __restrict__ outL,
                                                    float* __restrict__ outR,
                                                    int M, int K, int C, int col0) {
  const bf16_t* Bh = blockIdx.z ? BhR : BhL;
  const bf16_t* Bl = blockIdx.z ? BlR : BlL;
  const float* bias = blockIdx.z ? br : bl;
  float* out = blockIdx.z ? outR : outL;

  __shared__ __align__(16) bf16_t AsH[4 * 128 * 8];   // 8KB
  __shared__ __align__(16) bf16_t AsL[4 * 128 * 8];   // 8KB
  __shared__ __align__(16) bf16_t BsH[4 * 256 * 8];   // 16KB
  __shared__ __align__(16) bf16_t BsL[4 * 256 * 8];   // 16KB

  int tid = threadIdx.x;
  int wave = tid >> 6, lane = tid & 63;
  int l31 = lane & 31, lhalf = lane >> 5;
  int mt = blockIdx.y;              // 128-row A tile
  int nt0 = blockIdx.x * 2;         // two 128-col B tiles
  int m0 = mt * 128, n0 = blockIdx.x * 256;
  int kchunks = K >> 3;

  const bf16_t* Ah = Xh + (size_t)mt * K * 128;
  const bf16_t* Al = Xl + (size_t)mt * K * 128;

  f32x16 acc[4][2];
#pragma unroll
  for (int i = 0; i < 4; i++)
#pragma unroll
    for (int j = 0; j < 2; j++)
#pragma unroll
      for (int r = 0; r < 16; r++) acc[i][j][r] = 0.f;

  for (int k0 = 0; k0 < K; k0 += 32) {
    int kc0 = k0 >> 3;
    // A staging: 512 float4 slots per buffer (4 chunks x 128 rows)
#pragma unroll
    for (int r = 0; r < 2; r++) {
      int idx = tid + 256 * r;
      int c = idx >> 7, ml = idx & 127;
      size_t aoff = ((size_t)(kc0 + c)) * 1024 + (size_t)ml * 8;
      int li = (c * 128 + ml) * 8;
      *(float4*)&AsH[li] = *(const float4*)(Ah + aoff);
      *(float4*)&AsL[li] = *(const float4*)(Al + aoff);
    }
    // B staging: 1024 slots per buffer (4 chunks x 256 cols, 2 n-tiles)
#pragma unroll
    for (int r = 0; r < 4; r++) {
      int idx = tid + 256 * r;
      int c = idx >> 8, nl = idx & 255;
      int nt = nt0 + (nl >> 7);
      size_t boff = ((size_t)(nt * kchunks + kc0 + c)) * 1024 + (size_t)(nl & 127) * 8;
      int li = (c * 256 + nl) * 8;
      *(float4*)&BsH[li] = *(const float4*)(Bh + boff);
      *(float4*)&BsL[li] = *(const float4*)(Bl + boff);
    }
    __syncthreads();

#pragma unroll
    for (int s = 0; s < 2; s++) {
      int c = s * 2 + lhalf;
      bf16x8 ah[4], al[4], bh[2], blo[2];
#pragma unroll
      for (int i = 0; i < 4; i++) {
        int abase = (c * 128 + i * 32 + l31) * 8;
        ah[i] = *(const bf16x8*)&AsH[abase];
        al[i] = *(const bf16x8*)&AsL[abase];
      }
#pragma unroll
      for (int j = 0; j < 2; j++) {
        int bbase = (c * 256 + wave * 64 + j * 32 + l31) * 8;
        bh[j] = *(const bf16x8*)&BsH[bbase];
        blo[j] = *(const bf16x8*)&BsL[bbase];
      }
#pragma unroll
      for (int i = 0; i < 4; i++)
#pragma unroll
        for (int j = 0; j < 2; j++) {
          acc[i][j] = __builtin_amdgcn_mfma_f32_32x32x16_bf16(ah[i], bh[j], acc[i][j], 0, 0, 0);
          acc[i][j] = __builtin_amdgcn_mfma_f32_32x32x16_bf16(ah[i], blo[j], acc[i][j], 0, 0, 0);
          acc[i][j] = __builtin_amdgcn_mfma_f32_32x32x16_bf16(al[i], bh[j], acc[i][j], 0, 0, 0);
        }
    }
    __syncthreads();
  }

  // epilogue: C/D layout col=lane&31, row=(r&3)+8*(r>>2)+4*(lane>>5)
#pragma unroll
  for (int j = 0; j < 2; j++) {
    int n = n0 + wave * 64 + j * 32 + l31;
    if (n >= C) continue;
    float bv = bias[col0 + n];
#pragma unroll
    for (int i = 0; i < 4; i++) {
#pragma unroll
      for (int r = 0; r < 16; r++) {
        int row = (r & 3) + 8 * (r >> 2) + 4 * lhalf;
        int m = m0 + i * 32 + row;
        if (m < M) out[(size_t)m * C + n] = acc[i][j][r] + bv;
      }
    }
  }
}

// ---------------- fp32 GEMM (layer 1, K=4), grouped heads ----------------

#define BM 128
#define BN 128
#define BK 16
#define LDA (BM + 4)
#define LDB (BN + 4)

__global__ __launch_bounds__(256) void gemm128(const float* __restrict__ X,
                                               const float* __restrict__ Wl,
                                               const float* __restrict__ Wr,
                                               const float* __restrict__ bl,
                                               const float* __restrict__ br,
                                               float* __restrict__ outL,
                                               float* __restrict__ outR,
                                               int M, int K, int C, int ldW, int col0) {
  const float* W = blockIdx.z ? Wr : Wl;
  const float* bias = blockIdx.z ? br : bl;
  float* out = blockIdx.z ? outR : outL;

  __shared__ __align__(16) float As[BK][LDA];
  __shared__ __align__(16) float Bs[BK][LDB];

  int t = threadIdx.x;
  int tx = t & 15, ty = t >> 4;
  int m0 = blockIdx.y * BM, n0 = blockIdx.x * BN;

  float acc00[4][4] = {}, acc01[4][4] = {}, acc10[4][4] = {}, acc11[4][4] = {};

  for (int k0 = 0; k0 < K; k0 += BK) {
    {
      int kk = (t & 3) * 4;
#pragma unroll
      for (int p = 0; p < 2; p++) {
        int row = (t >> 2) + p * 64;
        int m = m0 + row;
        float4 v = make_float4(0.f, 0.f, 0.f, 0.f);
        if (m < M && (k0 + kk) < K)
          v = *(const float4*)(X + (size_t)m * K + k0 + kk);
        As[kk + 0][row] = v.x; As[kk + 1][row] = v.y;
        As[kk + 2][row] = v.z; As[kk + 3][row] = v.w;
      }
    }
    {
      int kk = t >> 4;
#pragma unroll
      for (int q = 0; q < 2; q++) {
        int cn = (t & 15) * 4 + q * 64;
        int n = n0 + cn;
        float4 v = make_float4(0.f, 0.f, 0.f, 0.f);
        if ((k0 + kk) < K && n + 3 < C)
          v = *(const float4*)(W + (size_t)(k0 + kk) * ldW + col0 + n);
        *(float4*)&Bs[kk][cn] = v;
      }
    }
    __syncthreads();

    int kmax = min(BK, K - k0);
    for (int kk = 0; kk < kmax; kk++) {
      float4 a0 = *(const float4*)&As[kk][ty * 4];
      float4 a1 = *(const float4*)&As[kk][64 + ty * 4];
      float4 b0 = *(const float4*)&Bs[kk][tx * 4];
      float4 b1 = *(const float4*)&Bs[kk][64 + tx * 4];
      float af0[4] = {a0.x, a0.y, a0.z, a0.w};
      float af1[4] = {a1.x, a1.y, a1.z, a1.w};
      float bf0[4] = {b0.x, b0.y, b0.z, b0.w};
      float bf1[4] = {b1.x, b1.y, b1.z, b1.w};
#pragma unroll
      for (int i = 0; i < 4; i++)
#pragma unroll
        for (int j = 0; j < 4; j++) {
          acc00[i][j] += af0[i] * bf0[j];
          acc01[i][j] += af0[i] * bf1[j];
          acc10[i][j] += af1[i] * bf0[j];
          acc11[i][j] += af1[i] * bf1[j];
        }
    }
    __syncthreads();
  }

#pragma unroll
  for (int ma = 0; ma < 2; ma++) {
#pragma unroll
    for (int i = 0; i < 4; i++) {
      int m = m0 + ma * 64 + ty * 4 + i;
      if (m >= M) continue;
#pragma unroll
      for (int nb = 0; nb < 2; nb++) {
        int n = n0 + nb * 64 + tx * 4;
        float (*blk)[4] = (ma == 0) ? ((nb == 0) ? acc00 : acc01)
                                    : ((nb == 0) ? acc10 : acc11);
        if (n + 3 < C) {
          float4 bv = *(const float4*)(bias + col0 + n);
          float4 o = make_float4(blk[i][0] + bv.x, blk[i][1] + bv.y,
                                 blk[i][2] + bv.z, blk[i][3] + bv.w);
          *(float4*)(out + (size_t)m * C + n) = o;
        }
      }
    }
  }
}

// ---------------- one-pass fused edge kernel (online softmax) ----------------

template <int F4PT>
__global__ __launch_bounds__(256) void edge_fused_kernel(const int* __restrict__ row_ptr,
                                                         const int* __restrict__ col_src,
                                                         const float* __restrict__ xl,
                                                         const float* __restrict__ xr,
                                                         int ld4, int coff4,
                                                         const float* __restrict__ att,
                                                         float* __restrict__ acc,
                                                         int C, int head) {
  int node = blockIdx.x;
  int tid = threadIdx.x;
  int wave = tid >> 6, lane = tid & 63;
  int C4 = C >> 2;
  int s = row_ptr[node], t = row_ptr[node + 1];

  __shared__ __align__(16) float4 slab[4][F4PT * 64];
  __shared__ float mred[4], dred[4];

  float4 xr4[F4PT], a4[F4PT], o4[F4PT];
  const float4* xrp = (const float4*)xr + (size_t)node * ld4 + coff4;
  const float4* ap = (const float4*)att;
#pragma unroll
  for (int k = 0; k < F4PT; k++) {
    int c4 = k * 64 + lane;
    bool ok = (c4 < C4);
    xr4[k] = ok ? xrp[c4] : make_float4(0.f, 0.f, 0.f, 0.f);
    a4[k] = ok ? ap[c4] : make_float4(0.f, 0.f, 0.f, 0.f);
    o4[k] = make_float4(0.f, 0.f, 0.f, 0.f);
  }
  float m = -1e30f, den = 0.f;

  for (int j = s + wave; j < t; j += 4) {
    int src = col_src[j];
    const float4* xlp = (const float4*)xl + (size_t)src * ld4 + coff4;
    float4 x4[F4PT];
    float e = 0.f;
#pragma unroll
    for (int k = 0; k < F4PT; k++) {
      int c4 = k * 64 + lane;
      x4[k] = (c4 < C4) ? xlp[c4] : make_float4(0.f, 0.f, 0.f, 0.f);
      float v;
      v = x4[k].x + xr4[k].x; v = fmaxf(v, 0.f) + SLOPE_ATT * fminf(v, 0.f); e += a4[k].x * v;
      v = x4[k].y + xr4[k].y; v = fmaxf(v, 0.f) + SLOPE_ATT * fminf(v, 0.f); e += a4[k].y * v;
      v = x4[k].z + xr4[k].z; v = fmaxf(v, 0.f) + SLOPE_ATT * fminf(v, 0.f); e += a4[k].z * v;
      v = x4[k].w + xr4[k].w; v = fmaxf(v, 0.f) + SLOPE_ATT * fminf(v, 0.f); e += a4[k].w * v;
    }
#pragma unroll
    for (int off = 1; off < 64; off <<= 1) e += __shfl_xor(e, off, 64);

    if (e <= m) {  // wave-uniform branch
      float p = expf(e - m);
      den += p;
#pragma unroll
      for (int k = 0; k < F4PT; k++) {
        o4[k].x += p * x4[k].x; o4[k].y += p * x4[k].y;
        o4[k].z += p * x4[k].z; o4[k].w += p * x4[k].w;
      }
    } else {
      float scale = expf(m - e);  // m=-1e30 first time -> 0
      den = den * scale + 1.f;
#pragma unroll
      for (int k = 0; k < F4PT; k++) {
        o4[k].x = o4[k].x * scale + x4[k].x; o4[k].y = o4[k].y * scale + x4[k].y;
        o4[k].z = o4[k].z * scale + x4[k].z; o4[k].w = o4[k].w * scale + x4[k].w;
      }
      m = e;
    }
  }

  if (lane == 0) { mred[wave] = m; dred[wave] = den; }
  __syncthreads();
  float M2 = fmaxf(fmaxf(mred[0], mred[1]), fmaxf(mred[2], mred[3]));
  float dtot = dred[0] * expf(mred[0] - M2) + dred[1] * expf(mred[1] - M2) +
               dred[2] * expf(mred[2] - M2) + dred[3] * expf(mred[3] - M2);
  float f = expf(m - M2);
#pragma unroll
  for (int k = 0; k < F4PT; k++) {
    float4 w4 = make_float4(o4[k].x * f, o4[k].y * f, o4[k].z * f, o4[k].w * f);
    slab[wave][k * 64 + lane] = w4;
  }
  __syncthreads();
  float inv = 1.0f / dtot;
  float4* accp = (float4*)(acc + (size_t)node * C);
  for (int c4 = tid; c4 < C4; c4 += 256) {
    float4 s0 = slab[0][c4], s1 = slab[1][c4], s2 = slab[2][c4], s3 = slab[3][c4];
    float4 val = make_float4(((s0.x + s1.x) + (s2.x + s3.x)) * inv,
                             ((s0.y + s1.y) + (s2.y + s3.y)) * inv,
                             ((s0.z + s1.z) + (s2.z + s3.z)) * inv,
                             ((s0.w + s1.w) + (s2.w + s3.w)) * inv);
    if (head == 0) {
      accp[c4] = val;
    } else {
      float4 prev = accp[c4];
      accp[c4] = make_float4(prev.x + val.x, prev.y + val.y, prev.z + val.z, prev.w + val.w);
    }
  }
}

// ---------------- finalize: mean over heads + bias (+ leaky relu) ----------------

__global__ __launch_bounds__(256) void finalize_kernel(const float* __restrict__ acc,
                                                       const float* __restrict__ bias,
                                                       float* __restrict__ out,
                                                       int total, int C, int apply_act) {
  int i = blockIdx.x * 256 + threadIdx.x;
  if (i >= total) return;
  int c = i % C;
  float v = acc[i] * (1.0f / 32.0f) + bias[c];
  if (apply_act) v = (v >= 0.f) ? v : SLOPE_ACT * v;
  out[i] = v;
}

// ---------------- host ----------------

static inline size_t align16(size_t x) { return (x + 15) & ~size_t(15); }

extern "C" void kernel_launch(void* const* d_in, const int* in_sizes, int n_in,
                              void* d_out, int out_size, void* d_ws, size_t ws_size,
                              hipStream_t stream) {
  const float* x0 = (const float*)d_in[0];
  const int* ei = (const int*)d_in[1];

  const int N = in_sizes[0] / 4;       // 10000
  const int E = in_sizes[1] / 2;       // 160000
  const int ETOT = E + N;              // 170000
  const int MTILES = (N + 127) / 128;  // 79 -> use 80 for grid.y evenness
  const int MPAD = 80 * 128;           // 10240

  struct LayerP { const float *Wl, *bl, *Wr, *br, *att, *bias; int fi, fo; };
  LayerP L[3] = {
      {(const float*)d_in[2],  (const float*)d_in[3],  (const float*)d_in[4],
       (const float*)d_in[5],  (const float*)d_in[6],  (const float*)d_in[7],  4, 128},
      {(const float*)d_in[8],  (const float*)d_in[9],  (const float*)d_in[10],
       (const float*)d_in[11], (const float*)d_in[12], (const float*)d_in[13], 128, 512},
      {(const float*)d_in[14], (const float*)d_in[15], (const float*)d_in[16],
       (const float*)d_in[17], (const float*)d_in[18], (const float*)d_in[19], 512, 1028},
  };

  char* w = (char*)d_ws;
  auto alloc = [&](size_t bytes) { char* p = w; w += align16(bytes); return p; };
  int* counts   = (int*)alloc((size_t)N * 4);
  int* row_ptr  = (int*)alloc((size_t)(N + 1) * 4);
  int* cursor   = (int*)alloc((size_t)N * 4);
  int* col_src  = (int*)alloc((size_t)ETOT * 4);
  int* col_dst  = (int*)alloc((size_t)ETOT * 4);
  float* xlh    = (float*)alloc((size_t)N * 1028 * 4);
  float* xrh    = (float*)alloc((size_t)N * 1028 * 4);
  float* h1     = (float*)alloc((size_t)N * 128 * 4);
  float* h2     = (float*)alloc((size_t)N * 512 * 4);
  float* acc12  = (float*)alloc((size_t)N * 512 * 4);
  bf16_t* xph   = (bf16_t*)alloc((size_t)MPAD * 512 * 2);
  bf16_t* xpl   = (bf16_t*)alloc((size_t)MPAD * 512 * 2);
  // layer-3 per-head packed W (Npad=1280, K=512)
  const size_t WPK3 = (size_t)1280 * 512;
  bf16_t* w3hL  = (bf16_t*)alloc(WPK3 * 2);
  bf16_t* w3lL  = (bf16_t*)alloc(WPK3 * 2);
  bf16_t* w3hR  = (bf16_t*)alloc(WPK3 * 2);
  bf16_t* w3lR  = (bf16_t*)alloc(WPK3 * 2);
  // layer-2 all-heads packed W (Npad=512, K=128): 32*512*128 = 2.1M elems each
  const size_t WPK2 = (size_t)HEADS * 512 * 128;
  bf16_t* w2hL  = (bf16_t*)alloc(WPK2 * 2);
  bf16_t* w2lL  = (bf16_t*)alloc(WPK2 * 2);
  bf16_t* w2hR  = (bf16_t*)alloc(WPK2 * 2);
  bf16_t* w2lR  = (bf16_t*)alloc(WPK2 * 2);

  // ---- CSR build (dst-sorted) ----
  init_counts_kernel<<<(N + 255) / 256, 256, 0, stream>>>(counts, N);
  count_kernel<<<(E + 255) / 256, 256, 0, stream>>>(ei + E, counts, E);
  scan_kernel<<<1, 1024, 0, stream>>>(counts, row_ptr, cursor, N);
  scatter_edges_kernel<<<(E + 255) / 256, 256, 0, stream>>>(ei, cursor, col_src, col_dst, E);
  scatter_loops_kernel<<<(N + 255) / 256, 256, 0, stream>>>(cursor, col_src, col_dst, N);

  float* layer_acc[3] = {acc12, acc12, (float*)d_out};

  // ---- layer 1 (fp32 GEMM, 8-head groups of C=1024 into xlh/xrh) ----
  {
    int C = 128;
    float* acc = layer_acc[0];
    for (int g = 0; g < 4; g++) {
      dim3 ggrid(8, (N + 127) / 128, 2);
      gemm128<<<ggrid, 256, 0, stream>>>(x0, L[0].Wl, L[0].Wr, L[0].bl, L[0].br,
                                         xlh, xrh, N, 4, 1024, HEADS * C, g * 1024);
      for (int hh = 0; hh < 8; hh++) {
        int head = g * 8 + hh;
        edge_fused_kernel<1><<<N, 256, 0, stream>>>(row_ptr, col_src, xlh, xrh,
                                                    256, hh * 32,
                                                    L[0].att + (size_t)head * C, acc, C, head);
      }
    }
    finalize_kernel<<<((size_t)N * C + 255) / 256, 256, 0, stream>>>(acc, L[0].bias, h1,
                                                                     N * C, C, 1);
  }

  // ---- layer 2 (K=128, C=512, Npad=512; all-heads W prepack) ----
  {
    int fi = 128, C = 512, ldW = HEADS * C, Npadh = 512;
    float* acc = layer_acc[1];
    int total = MPAD * (fi >> 3);
    cvt_pack_kernel<<<(total + 255) / 256, 256, 0, stream>>>(h1, xph, xpl, N, MPAD, fi);
    int wtotal = HEADS * Npadh * (fi >> 3);
    dim3 wgrid((wtotal + 255) / 256, 2);
    pack_w_all_kernel<<<wgrid, 256, 0, stream>>>(L[1].Wl, L[1].Wr, w2hL, w2lL, w2hR, w2lR,
                                                 fi, C, Npadh, ldW);
    size_t hstride = (size_t)Npadh * fi;
    for (int h = 0; h < HEADS; h++) {
      dim3 ggrid(Npadh / 256, MPAD / 128, 2);
      gemm_mfma_v5<<<ggrid, 256, 0, stream>>>(xph, xpl,
                                              w2hL + h * hstride, w2lL + h * hstride,
                                              w2hR + h * hstride, w2lR + h * hstride,
                                              L[1].bl, L[1].br, xlh, xrh, N, fi, C, h * C);
      edge_fused_kernel<2><<<N, 256, 0, stream>>>(row_ptr, col_src, xlh, xrh, C / 4, 0,
                                                  L[1].att + (size_t)h * C, acc, C, h);
    }
    finalize_kernel<<<((size_t)N * C + 255) / 256, 256, 0, stream>>>(acc, L[1].bias, h2,
                                                                     N * C, C, 1);
  }

  // ---- layer 3 (K=512, C=1028, Npad=1280; per-head W pack) ----
  {
    int fi = 512, C = 1028, ldW = HEADS * C, Npadh = 1280;
    float* acc = layer_acc[2];
    int total = MPAD * (fi >> 3);
    cvt_pack_kernel<<<(total + 255) / 256, 256, 0, stream>>>(h2, xph, xpl, N, MPAD, fi);
    for (int h = 0; h < HEADS; h++) {
      int col0 = h * C;
      int wtotal = Npadh * (fi >> 3);
      dim3 wgrid((wtotal + 255) / 256, 2);
      pack_w_kernel<<<wgrid, 256, 0, stream>>>(L[2].Wl, L[2].Wr, w3hL, w3lL, w3hR, w3lR,
                                               fi, C, Npadh, ldW, col0);
      dim3 ggrid(Npadh / 256, MPAD / 128, 2);
      gemm_mfma_v5<<<ggrid, 256, 0, stream>>>(xph, xpl, w3hL, w3lL, w3hR, w3lR,
                                              L[2].bl, L[2].br, xlh, xrh, N, fi, C, col0);
      edge_fused_kernel<5><<<N, 256, 0, stream>>>(row_ptr, col_src, xlh, xrh, C / 4, 0,
                                                  L[2].att + (size_t)h * C, acc, C, h);
    }
    finalize_kernel<<<((size_t)N * C + 255) / 256, 256, 0, stream>>>(acc, L[2].bias, (float*)d_out,
                                                                     N * C, C, 0);
  }
}

// Round 7
// 10334.366 us; speedup vs baseline: 1.3061x; 1.3061x over previous
//
#include <hip/hip_runtime.h>
#include <cstddef>
#include <cstdint>

// ---------------------------------------------------------------------------
// GATv2 x3 layers. R6:
//  - back to R3's 128x128 MFMA tile (best measured: concurrency > per-wave LDS
//    ratio; R4/R5 bigger tiles starved the grid -> MfmaUtil 18%, Occ 8.6%)
//  - head-batched GEMM launches: grid.z = 2 sides x G heads (G=2 l3, G=4 l2)
//  - global_load_lds width=16 DMA staging (no VGPR round-trip)
//  - split-bf16 (hi*hi + hi*lo + lo*hi) MFMA, fp32 accum; fused online-softmax
//    edge kernel; layer-1 fp32 GEMM grouped 8 heads/launch.
// ---------------------------------------------------------------------------

#define HEADS 32
#define SLOPE_ATT 0.2f
#define SLOPE_ACT 0.01f

typedef __bf16 bf16_t;
typedef __bf16 bf16x8 __attribute__((ext_vector_type(8)));
typedef float f32x16 __attribute__((ext_vector_type(16)));

#define GLDS16(gp, lp)                                                        \
  __builtin_amdgcn_global_load_lds(                                           \
      (const __attribute__((address_space(1))) void*)(gp),                    \
      (__attribute__((address_space(3))) void*)(lp), 16, 0, 0)

// ---------------- CSR build ----------------

__global__ __launch_bounds__(256) void init_counts_kernel(int* counts, int n) {
  int i = blockIdx.x * 256 + threadIdx.x;
  if (i < n) counts[i] = 1;  // self-loop
}

__global__ __launch_bounds__(256) void count_kernel(const int* __restrict__ dst, int* counts, int E) {
  int e = blockIdx.x * 256 + threadIdx.x;
  if (e < E) atomicAdd(&counts[dst[e]], 1);
}

__global__ __launch_bounds__(1024) void scan_kernel(const int* __restrict__ counts,
                                                    int* __restrict__ row_ptr,
                                                    int* __restrict__ cursor, int n) {
  __shared__ int sums[1024];
  int t = threadIdx.x;
  int per = (n + 1023) >> 10;
  int base = t * per;
  int s = 0;
  for (int i = 0; i < per; i++) { int idx = base + i; if (idx < n) s += counts[idx]; }
  sums[t] = s;
  __syncthreads();
  for (int off = 1; off < 1024; off <<= 1) {
    int v = (t >= off) ? sums[t - off] : 0;
    __syncthreads();
    sums[t] += v;
    __syncthreads();
  }
  int run = (t == 0) ? 0 : sums[t - 1];
  for (int i = 0; i < per; i++) {
    int idx = base + i;
    if (idx < n) { row_ptr[idx] = run; cursor[idx] = run; run += counts[idx]; }
  }
  if (t == 1023) row_ptr[n] = sums[1023];
}

__global__ __launch_bounds__(256) void scatter_edges_kernel(const int* __restrict__ ei, int* cursor,
                                                            int* col_src, int* col_dst, int E) {
  int e = blockIdx.x * 256 + threadIdx.x;
  if (e >= E) return;
  int src = ei[e], dst = ei[E + e];
  int pos = atomicAdd(&cursor[dst], 1);
  col_src[pos] = src;
  col_dst[pos] = dst;
}

__global__ __launch_bounds__(256) void scatter_loops_kernel(int* cursor, int* col_src, int* col_dst, int N) {
  int nid = blockIdx.x * 256 + threadIdx.x;
  if (nid >= N) return;
  int pos = atomicAdd(&cursor[nid], 1);
  col_src[pos] = nid;
  col_dst[pos] = nid;
}

// ---------------- split-bf16 pack: X[M,K] fp32 -> frag-major hi/lo ----------------
// index: (mtile*(K/8) + kchunk)*1024 + mlocal*8 + (k&7); Mpad = mtiles*128.

__global__ __launch_bounds__(256) void cvt_pack_kernel(const float* __restrict__ X,
                                                       bf16_t* __restrict__ hi,
                                                       bf16_t* __restrict__ lo,
                                                       int M, int Mpad, int K) {
  int t = blockIdx.x * 256 + threadIdx.x;
  int kchunks = K >> 3;
  int total = Mpad * kchunks;
  if (t >= total) return;
  int kc = t % kchunks;
  int m = t / kchunks;
  int mt = m >> 7, ml = m & 127;
  size_t o = ((size_t)(mt * kchunks + kc)) * 1024 + (size_t)ml * 8;
  float v[8];
  if (m < M) {
    float4 a = *(const float4*)(X + (size_t)m * K + kc * 8);
    float4 b = *(const float4*)(X + (size_t)m * K + kc * 8 + 4);
    v[0] = a.x; v[1] = a.y; v[2] = a.z; v[3] = a.w;
    v[4] = b.x; v[5] = b.y; v[6] = b.z; v[7] = b.w;
  } else {
#pragma unroll
    for (int i = 0; i < 8; i++) v[i] = 0.f;
  }
  union { bf16_t h[8]; float4 f; } uh, ul;
#pragma unroll
  for (int i = 0; i < 8; i++) {
    bf16_t h = (bf16_t)v[i];
    uh.h[i] = h;
    ul.h[i] = (bf16_t)(v[i] - (float)h);
  }
  *(float4*)(hi + o) = uh.f;
  *(float4*)(lo + o) = ul.f;
}

// ---------------- W pack, G heads starting at h0 ----------------
// head g slab at g*Npad*K; within slab: (ntile*(K/8)+kchunk)*1024 + nl*8 + k&7.

__global__ __launch_bounds__(256) void pack_w_group_kernel(const float* __restrict__ Wl,
                                                           const float* __restrict__ Wr,
                                                           bf16_t* __restrict__ hL, bf16_t* __restrict__ lL,
                                                           bf16_t* __restrict__ hR, bf16_t* __restrict__ lR,
                                                           int K, int C, int Npad, int ldW,
                                                           int h0, int G) {
  int side = blockIdx.y;
  const float* W = side ? Wr : Wl;
  bf16_t* Hi = side ? hR : hL;
  bf16_t* Lo = side ? lR : lL;
  int kchunks = K >> 3;
  int perhead = Npad * kchunks;
  int t = blockIdx.x * 256 + threadIdx.x;
  if (t >= G * perhead) return;
  int g = t / perhead, rem = t % perhead;
  int n = rem % Npad, kc = rem / Npad;
  int nt = n >> 7, nl = n & 127;
  size_t o = (size_t)g * Npad * K + ((size_t)(nt * kchunks + kc)) * 1024 + (size_t)nl * 8;
  int col0 = (h0 + g) * C;
  union { bf16_t hh[8]; float4 f; } uh, ul;
#pragma unroll
  for (int kk = 0; kk < 8; kk++) {
    int k = kc * 8 + kk;
    float v = (n < C) ? W[(size_t)k * ldW + col0 + n] : 0.f;
    bf16_t hv = (bf16_t)v;
    uh.hh[kk] = hv;
    ul.hh[kk] = (bf16_t)(v - (float)hv);
  }
  *(float4*)(Hi + o) = uh.f;
  *(float4*)(Lo + o) = ul.f;
}

// ---------------- MFMA GEMM 128x128, 256 thr, head-batched z, DMA staging ----
// z = g*2 + side. Wave owns 32-row band x 128 n; acc[4] f32x16 (64 VGPR).

__global__ __launch_bounds__(256) void gemm_mfma_v6(const bf16_t* __restrict__ Xh,
                                                    const bf16_t* __restrict__ Xl,
                                                    const bf16_t* __restrict__ BhL,
                                                    const bf16_t* __restrict__ BlL,
                                                    const bf16_t* __restrict__ BhR,
                                                    const bf16_t* __restrict__ BlR,
                                                    size_t bHeadStride,
                                                    const float* __restrict__ bl,
                                                    const float* __restrict__ br,
                                                    float* __restrict__ outL,
                                                    float* __restrict__ outR,
                                                    size_t outHeadStride,
                                                    int M, int K, int C, int h0) {
  int g = blockIdx.z >> 1, side = blockIdx.z & 1;
  const bf16_t* Bh = (side ? BhR : BhL) + (size_t)g * bHeadStride;
  const bf16_t* Bl = (side ? BlR : BlL) + (size_t)g * bHeadStride;
  const float* bias = side ? br : bl;
  float* out = (side ? outR : outL) + (size_t)g * outHeadStride;
  int col0 = (h0 + g) * C;

  __shared__ __align__(16) bf16_t AsH[4 * 128 * 8];   // 8KB each
  __shared__ __align__(16) bf16_t AsL[4 * 128 * 8];
  __shared__ __align__(16) bf16_t BsH[4 * 128 * 8];
  __shared__ __align__(16) bf16_t BsL[4 * 128 * 8];

  int tid = threadIdx.x;
  int wave = tid >> 6, lane = tid & 63;
  int l31 = lane & 31, lhalf = lane >> 5;
  int mt = blockIdx.y;
  int ntb = blockIdx.x * 128;
  int m0 = mt * 128;
  int kchunks = K >> 3;

  const bf16_t* Ah = Xh + (size_t)mt * K * 128;
  const bf16_t* Al = Xl + (size_t)mt * K * 128;
  const bf16_t* Bhp = Bh + (size_t)blockIdx.x * kchunks * 1024;
  const bf16_t* Blp = Bl + (size_t)blockIdx.x * kchunks * 1024;

  auto* asH3 = (__attribute__((address_space(3))) bf16_t*)AsH;
  auto* asL3 = (__attribute__((address_space(3))) bf16_t*)AsL;
  auto* bsH3 = (__attribute__((address_space(3))) bf16_t*)BsH;
  auto* bsL3 = (__attribute__((address_space(3))) bf16_t*)BsL;

  f32x16 acc[4];
#pragma unroll
  for (int i = 0; i < 4; i++)
#pragma unroll
    for (int r = 0; r < 16; r++) acc[i][r] = 0.f;

  for (int k0 = 0; k0 < K; k0 += 32) {
    int kc0 = k0 >> 3;
    // DMA staging: 4 kchunks x 128 rows x 16B frags; lane-contiguous both sides
#pragma unroll
    for (int r = 0; r < 2; r++) {
      int idx = tid + 256 * r;
      size_t off = ((size_t)(kc0 + (idx >> 7))) * 1024 + (size_t)(idx & 127) * 8;
      int li = idx * 8;
      GLDS16(Ah + off, asH3 + li);
      GLDS16(Al + off, asL3 + li);
      GLDS16(Bhp + off, bsH3 + li);
      GLDS16(Blp + off, bsL3 + li);
    }
    __syncthreads();

    // compute: 2 k16-steps, wave owns 32-row band, 4 n-tiles of 32
#pragma unroll
    for (int s = 0; s < 2; s++) {
      int c = s * 2 + lhalf;
      int abase = (c * 128 + wave * 32 + l31) * 8;
      bf16x8 ah = *(const bf16x8*)&AsH[abase];
      bf16x8 al = *(const bf16x8*)&AsL[abase];
#pragma unroll
      for (int nt = 0; nt < 4; nt++) {
        int bbase = (c * 128 + nt * 32 + l31) * 8;
        bf16x8 bh = *(const bf16x8*)&BsH[bbase];
        bf16x8 blo = *(const bf16x8*)&BsL[bbase];
        acc[nt] = __builtin_amdgcn_mfma_f32_32x32x16_bf16(ah, bh, acc[nt], 0, 0, 0);
        acc[nt] = __builtin_amdgcn_mfma_f32_32x32x16_bf16(ah, blo, acc[nt], 0, 0, 0);
        acc[nt] = __builtin_amdgcn_mfma_f32_32x32x16_bf16(al, bh, acc[nt], 0, 0, 0);
      }
    }
    __syncthreads();
  }

  // epilogue: C/D layout col=lane&31, row=(r&3)+8*(r>>2)+4*(lane>>5)
#pragma unroll
  for (int nt = 0; nt < 4; nt++) {
    int n = ntb + nt * 32 + l31;
    if (n >= C) continue;
    float bv = bias[col0 + n];
#pragma unroll
    for (int r = 0; r < 16; r++) {
      int row = (r & 3) + 8 * (r >> 2) + 4 * lhalf;
      int m = m0 + wave * 32 + row;
      if (m < M) out[(size_t)m * C + n] = acc[nt][r] + bv;
    }
  }
}

// ---------------- fp32 GEMM (layer 1, K=4), grouped heads ----------------

#define BM 128
#define BN 128
#define BK 16
#define LDA (BM + 4)
#define LDB (BN + 4)

__global__ __launch_bounds__(256) void gemm128(const float* __restrict__ X,
                                               const float* __restrict__ Wl,
                                               const float* __restrict__ Wr,
                                               const float* __restrict__ bl,
                                               const float* __restrict__ br,
                                               float* __restrict__ outL,
                                               float* __restrict__ outR,
                                               int M, int K, int C, int ldW, int col0) {
  const float* W = blockIdx.z ? Wr : Wl;
  const float* bias = blockIdx.z ? br : bl;
  float* out = blockIdx.z ? outR : outL;

  __shared__ __align__(16) float As[BK][LDA];
  __shared__ __align__(16) float Bs[BK][LDB];

  int t = threadIdx.x;
  int tx = t & 15, ty = t >> 4;
  int m0 = blockIdx.y * BM, n0 = blockIdx.x * BN;

  float acc00[4][4] = {}, acc01[4][4] = {}, acc10[4][4] = {}, acc11[4][4] = {};

  for (int k0 = 0; k0 < K; k0 += BK) {
    {
      int kk = (t & 3) * 4;
#pragma unroll
      for (int p = 0; p < 2; p++) {
        int row = (t >> 2) + p * 64;
        int m = m0 + row;
        float4 v = make_float4(0.f, 0.f, 0.f, 0.f);
        if (m < M && (k0 + kk) < K)
          v = *(const float4*)(X + (size_t)m * K + k0 + kk);
        As[kk + 0][row] = v.x; As[kk + 1][row] = v.y;
        As[kk + 2][row] = v.z; As[kk + 3][row] = v.w;
      }
    }
    {
      int kk = t >> 4;
#pragma unroll
      for (int q = 0; q < 2; q++) {
        int cn = (t & 15) * 4 + q * 64;
        int n = n0 + cn;
        float4 v = make_float4(0.f, 0.f, 0.f, 0.f);
        if ((k0 + kk) < K && n + 3 < C)
          v = *(const float4*)(W + (size_t)(k0 + kk) * ldW + col0 + n);
        *(float4*)&Bs[kk][cn] = v;
      }
    }
    __syncthreads();

    int kmax = min(BK, K - k0);
    for (int kk = 0; kk < kmax; kk++) {
      float4 a0 = *(const float4*)&As[kk][ty * 4];
      float4 a1 = *(const float4*)&As[kk][64 + ty * 4];
      float4 b0 = *(const float4*)&Bs[kk][tx * 4];
      float4 b1 = *(const float4*)&Bs[kk][64 + tx * 4];
      float af0[4] = {a0.x, a0.y, a0.z, a0.w};
      float af1[4] = {a1.x, a1.y, a1.z, a1.w};
      float bf0[4] = {b0.x, b0.y, b0.z, b0.w};
      float bf1[4] = {b1.x, b1.y, b1.z, b1.w};
#pragma unroll
      for (int i = 0; i < 4; i++)
#pragma unroll
        for (int j = 0; j < 4; j++) {
          acc00[i][j] += af0[i] * bf0[j];
          acc01[i][j] += af0[i] * bf1[j];
          acc10[i][j] += af1[i] * bf0[j];
          acc11[i][j] += af1[i] * bf1[j];
        }
    }
    __syncthreads();
  }

#pragma unroll
  for (int ma = 0; ma < 2; ma++) {
#pragma unroll
    for (int i = 0; i < 4; i++) {
      int m = m0 + ma * 64 + ty * 4 + i;
      if (m >= M) continue;
#pragma unroll
      for (int nb = 0; nb < 2; nb++) {
        int n = n0 + nb * 64 + tx * 4;
        float (*blk)[4] = (ma == 0) ? ((nb == 0) ? acc00 : acc01)
                                    : ((nb == 0) ? acc10 : acc11);
        if (n + 3 < C) {
          float4 bv = *(const float4*)(bias + col0 + n);
          float4 o = make_float4(blk[i][0] + bv.x, blk[i][1] + bv.y,
                                 blk[i][2] + bv.z, blk[i][3] + bv.w);
          *(float4*)(out + (size_t)m * C + n) = o;
        }
      }
    }
  }
}

// ---------------- one-pass fused edge kernel (online softmax) ----------------

template <int F4PT>
__global__ __launch_bounds__(256) void edge_fused_kernel(const int* __restrict__ row_ptr,
                                                         const int* __restrict__ col_src,
                                                         const float* __restrict__ xl,
                                                         const float* __restrict__ xr,
                                                         int ld4, int coff4,
                                                         const float* __restrict__ att,
                                                         float* __restrict__ acc,
                                                         int C, int head) {
  int node = blockIdx.x;
  int tid = threadIdx.x;
  int wave = tid >> 6, lane = tid & 63;
  int C4 = C >> 2;
  int s = row_ptr[node], t = row_ptr[node + 1];

  __shared__ __align__(16) float4 slab[4][F4PT * 64];
  __shared__ float mred[4], dred[4];

  float4 xr4[F4PT], a4[F4PT], o4[F4PT];
  const float4* xrp = (const float4*)xr + (size_t)node * ld4 + coff4;
  const float4* ap = (const float4*)att;
#pragma unroll
  for (int k = 0; k < F4PT; k++) {
    int c4 = k * 64 + lane;
    bool ok = (c4 < C4);
    xr4[k] = ok ? xrp[c4] : make_float4(0.f, 0.f, 0.f, 0.f);
    a4[k] = ok ? ap[c4] : make_float4(0.f, 0.f, 0.f, 0.f);
    o4[k] = make_float4(0.f, 0.f, 0.f, 0.f);
  }
  float m = -1e30f, den = 0.f;

  for (int j = s + wave; j < t; j += 4) {
    int src = col_src[j];
    const float4* xlp = (const float4*)xl + (size_t)src * ld4 + coff4;
    float4 x4[F4PT];
    float e = 0.f;
#pragma unroll
    for (int k = 0; k < F4PT; k++) {
      int c4 = k * 64 + lane;
      x4[k] = (c4 < C4) ? xlp[c4] : make_float4(0.f, 0.f, 0.f, 0.f);
      float v;
      v = x4[k].x + xr4[k].x; v = fmaxf(v, 0.f) + SLOPE_ATT * fminf(v, 0.f); e += a4[k].x * v;
      v = x4[k].y + xr4[k].y; v = fmaxf(v, 0.f) + SLOPE_ATT * fminf(v, 0.f); e += a4[k].y * v;
      v = x4[k].z + xr4[k].z; v = fmaxf(v, 0.f) + SLOPE_ATT * fminf(v, 0.f); e += a4[k].z * v;
      v = x4[k].w + xr4[k].w; v = fmaxf(v, 0.f) + SLOPE_ATT * fminf(v, 0.f); e += a4[k].w * v;
    }
#pragma unroll
    for (int off = 1; off < 64; off <<= 1) e += __shfl_xor(e, off, 64);

    if (e <= m) {  // wave-uniform branch
      float p = expf(e - m);
      den += p;
#pragma unroll
      for (int k = 0; k < F4PT; k++) {
        o4[k].x += p * x4[k].x; o4[k].y += p * x4[k].y;
        o4[k].z += p * x4[k].z; o4[k].w += p * x4[k].w;
      }
    } else {
      float scale = expf(m - e);  // m=-1e30 first time -> 0
      den = den * scale + 1.f;
#pragma unroll
      for (int k = 0; k < F4PT; k++) {
        o4[k].x = o4[k].x * scale + x4[k].x; o4[k].y = o4[k].y * scale + x4[k].y;
        o4[k].z = o4[k].z * scale + x4[k].z; o4[k].w = o4[k].w * scale + x4[k].w;
      }
      m = e;
    }
  }

  if (lane == 0) { mred[wave] = m; dred[wave] = den; }
  __syncthreads();
  float M2 = fmaxf(fmaxf(mred[0], mred[1]), fmaxf(mred[2], mred[3]));
  float dtot = dred[0] * expf(mred[0] - M2) + dred[1] * expf(mred[1] - M2) +
               dred[2] * expf(mred[2] - M2) + dred[3] * expf(mred[3] - M2);
  float f = expf(m - M2);
#pragma unroll
  for (int k = 0; k < F4PT; k++) {
    float4 w4 = make_float4(o4[k].x * f, o4[k].y * f, o4[k].z * f, o4[k].w * f);
    slab[wave][k * 64 + lane] = w4;
  }
  __syncthreads();
  float inv = 1.0f / dtot;
  float4* accp = (float4*)(acc + (size_t)node * C);
  for (int c4 = tid; c4 < C4; c4 += 256) {
    float4 s0 = slab[0][c4], s1 = slab[1][c4], s2 = slab[2][c4], s3 = slab[3][c4];
    float4 val = make_float4(((s0.x + s1.x) + (s2.x + s3.x)) * inv,
                             ((s0.y + s1.y) + (s2.y + s3.y)) * inv,
                             ((s0.z + s1.z) + (s2.z + s3.z)) * inv,
                             ((s0.w + s1.w) + (s2.w + s3.w)) * inv);
    if (head == 0) {
      accp[c4] = val;
    } else {
      float4 prev = accp[c4];
      accp[c4] = make_float4(prev.x + val.x, prev.y + val.y, prev.z + val.z, prev.w + val.w);
    }
  }
}

// ---------------- finalize: mean over heads + bias (+ leaky relu) ----------------

__global__ __launch_bounds__(256) void finalize_kernel(const float* __restrict__ acc,
                                                       const float* __restrict__ bias,
                                                       float* __restrict__ out,
                                                       int total, int C, int apply_act) {
  int i = blockIdx.x * 256 + threadIdx.x;
  if (i >= total) return;
  int c = i % C;
  float v = acc[i] * (1.0f / 32.0f) + bias[c];
  if (apply_act) v = (v >= 0.f) ? v : SLOPE_ACT * v;
  out[i] = v;
}

// ---------------- host ----------------

static inline size_t align16(size_t x) { return (x + 15) & ~size_t(15); }

extern "C" void kernel_launch(void* const* d_in, const int* in_sizes, int n_in,
                              void* d_out, int out_size, void* d_ws, size_t ws_size,
                              hipStream_t stream) {
  const float* x0 = (const float*)d_in[0];
  const int* ei = (const int*)d_in[1];

  const int N = in_sizes[0] / 4;       // 10000
  const int E = in_sizes[1] / 2;       // 160000
  const int ETOT = E + N;              // 170000
  const int MTILES = (N + 127) / 128;  // 79
  const int MPAD = MTILES * 128;       // 10112

  struct LayerP { const float *Wl, *bl, *Wr, *br, *att, *bias; int fi, fo; };
  LayerP L[3] = {
      {(const float*)d_in[2],  (const float*)d_in[3],  (const float*)d_in[4],
       (const float*)d_in[5],  (const float*)d_in[6],  (const float*)d_in[7],  4, 128},
      {(const float*)d_in[8],  (const float*)d_in[9],  (const float*)d_in[10],
       (const float*)d_in[11], (const float*)d_in[12], (const float*)d_in[13], 128, 512},
      {(const float*)d_in[14], (const float*)d_in[15], (const float*)d_in[16],
       (const float*)d_in[17], (const float*)d_in[18], (const float*)d_in[19], 512, 1028},
  };

  char* w = (char*)d_ws;
  auto alloc = [&](size_t bytes) { char* p = w; w += align16(bytes); return p; };
  int* counts   = (int*)alloc((size_t)N * 4);
  int* row_ptr  = (int*)alloc((size_t)(N + 1) * 4);
  int* cursor   = (int*)alloc((size_t)N * 4);
  int* col_src  = (int*)alloc((size_t)ETOT * 4);
  int* col_dst  = (int*)alloc((size_t)ETOT * 4);
  // xlh/xrh: sized for max slab group = max(2*1028, 4*512, 1024) * N floats
  float* xlh    = (float*)alloc((size_t)N * 2056 * 4);
  float* xrh    = (float*)alloc((size_t)N * 2056 * 4);
  float* h1     = (float*)alloc((size_t)N * 128 * 4);
  float* h2     = (float*)alloc((size_t)N * 512 * 4);
  float* acc12  = (float*)alloc((size_t)N * 512 * 4);
  bf16_t* xph   = (bf16_t*)alloc((size_t)MPAD * 512 * 2);
  bf16_t* xpl   = (bf16_t*)alloc((size_t)MPAD * 512 * 2);
  // layer-3 group packed W (G=2 heads, Npad=1152, K=512)
  const size_t WPK3 = (size_t)2 * 1152 * 512;
  bf16_t* w3hL  = (bf16_t*)alloc(WPK3 * 2);
  bf16_t* w3lL  = (bf16_t*)alloc(WPK3 * 2);
  bf16_t* w3hR  = (bf16_t*)alloc(WPK3 * 2);
  bf16_t* w3lR  = (bf16_t*)alloc(WPK3 * 2);
  // layer-2 all-heads packed W (Npad=512, K=128)
  const size_t WPK2 = (size_t)HEADS * 512 * 128;
  bf16_t* w2hL  = (bf16_t*)alloc(WPK2 * 2);
  bf16_t* w2lL  = (bf16_t*)alloc(WPK2 * 2);
  bf16_t* w2hR  = (bf16_t*)alloc(WPK2 * 2);
  bf16_t* w2lR  = (bf16_t*)alloc(WPK2 * 2);

  // ---- CSR build (dst-sorted) ----
  init_counts_kernel<<<(N + 255) / 256, 256, 0, stream>>>(counts, N);
  count_kernel<<<(E + 255) / 256, 256, 0, stream>>>(ei + E, counts, E);
  scan_kernel<<<1, 1024, 0, stream>>>(counts, row_ptr, cursor, N);
  scatter_edges_kernel<<<(E + 255) / 256, 256, 0, stream>>>(ei, cursor, col_src, col_dst, E);
  scatter_loops_kernel<<<(N + 255) / 256, 256, 0, stream>>>(cursor, col_src, col_dst, N);

  // ---- layer 1 (fp32 GEMM, 8-head groups of C=1024 into xlh/xrh) ----
  {
    int C = 128;
    float* acc = acc12;
    for (int g = 0; g < 4; g++) {
      dim3 ggrid(8, MTILES, 2);
      gemm128<<<ggrid, 256, 0, stream>>>(x0, L[0].Wl, L[0].Wr, L[0].bl, L[0].br,
                                         xlh, xrh, N, 4, 1024, HEADS * C, g * 1024);
      for (int hh = 0; hh < 8; hh++) {
        int head = g * 8 + hh;
        edge_fused_kernel<1><<<N, 256, 0, stream>>>(row_ptr, col_src, xlh, xrh,
                                                    256, hh * 32,
                                                    L[0].att + (size_t)head * C, acc, C, head);
      }
    }
    finalize_kernel<<<((size_t)N * C + 255) / 256, 256, 0, stream>>>(acc, L[0].bias, h1,
                                                                     N * C, C, 1);
  }

  // ---- layer 2 (K=128, C=512, Npad=512; all-heads prepack; G=4 heads/launch) ----
  {
    int fi = 128, C = 512, ldW = HEADS * C, Npadh = 512, G = 4;
    float* acc = acc12;
    size_t NC = (size_t)N * C;
    int total = MPAD * (fi >> 3);
    cvt_pack_kernel<<<(total + 255) / 256, 256, 0, stream>>>(h1, xph, xpl, N, MPAD, fi);
    int wtotal = HEADS * Npadh * (fi >> 3);
    dim3 wgrid((wtotal + 255) / 256, 2);
    pack_w_group_kernel<<<wgrid, 256, 0, stream>>>(L[1].Wl, L[1].Wr, w2hL, w2lL, w2hR, w2lR,
                                                   fi, C, Npadh, ldW, 0, HEADS);
    size_t hstride = (size_t)Npadh * fi;
    for (int h0 = 0; h0 < HEADS; h0 += G) {
      dim3 ggrid(Npadh / 128, MTILES, 2 * G);
      gemm_mfma_v6<<<ggrid, 256, 0, stream>>>(xph, xpl,
                                              w2hL + h0 * hstride, w2lL + h0 * hstride,
                                              w2hR + h0 * hstride, w2lR + h0 * hstride,
                                              hstride, L[1].bl, L[1].br,
                                              xlh, xrh, NC, N, fi, C, h0);
      for (int g = 0; g < G; g++) {
        int head = h0 + g;
        edge_fused_kernel<2><<<N, 256, 0, stream>>>(row_ptr, col_src,
                                                    xlh + g * NC, xrh + g * NC, C / 4, 0,
                                                    L[1].att + (size_t)head * C, acc, C, head);
      }
    }
    finalize_kernel<<<((size_t)N * C + 255) / 256, 256, 0, stream>>>(acc, L[1].bias, h2,
                                                                     N * C, C, 1);
  }

  // ---- layer 3 (K=512, C=1028, Npad=1152; G=2 heads/launch, per-group pack) ----
  {
    int fi = 512, C = 1028, ldW = HEADS * C, Npadh = 1152, G = 2;
    float* acc = (float*)d_out;
    size_t NC = (size_t)N * C;
    int total = MPAD * (fi >> 3);
    cvt_pack_kernel<<<(total + 255) / 256, 256, 0, stream>>>(h2, xph, xpl, N, MPAD, fi);
    size_t hstride = (size_t)Npadh * fi;
    for (int h0 = 0; h0 < HEADS; h0 += G) {
      int wtotal = G * Npadh * (fi >> 3);
      dim3 wgrid((wtotal + 255) / 256, 2);
      pack_w_group_kernel<<<wgrid, 256, 0, stream>>>(L[2].Wl, L[2].Wr, w3hL, w3lL, w3hR, w3lR,
                                                     fi, C, Npadh, ldW, h0, G);
      dim3 ggrid(Npadh / 128, MTILES, 2 * G);
      gemm_mfma_v6<<<ggrid, 256, 0, stream>>>(xph, xpl, w3hL, w3lL, w3hR, w3lR,
                                              hstride, L[2].bl, L[2].br,
                                              xlh, xrh, NC, N, fi, C, h0);
      for (int g = 0; g < G; g++) {
        int head = h0 + g;
        edge_fused_kernel<5><<<N, 256, 0, stream>>>(row_ptr, col_src,
                                                    xlh + g * NC, xrh + g * NC, C / 4, 0,
                                                    L[2].att + (size_t)head * C, acc, C, head);
      }
    }
    finalize_kernel<<<((size_t)N * C + 255) / 256, 256, 0, stream>>>(acc, L[2].bias, (float*)d_out,
                                                                     N * C, C, 0);
  }
}